// Round 1
// 471.037 us; speedup vs baseline: 1.1337x; 1.1337x over previous
//
#include <hip/hip_runtime.h>
#include <hip/hip_bf16.h>
#include <stdint.h>

#define NN 8192
#define DIN 512
#define DOUT 256
#define NSPLIT 8
#define STRIP (NN / NSPLIT) /* 1024 */
#define NSTEP (STRIP / 32)  /* 32 */
#define LOG2E 1.4426950408889634f

typedef short short8 __attribute__((ext_vector_type(8)));
typedef float floatx4 __attribute__((ext_vector_type(4)));

__device__ __forceinline__ unsigned short f2bf_rne(float x) {
  unsigned u = __float_as_uint(x);
  u += 0x7fffu + ((u >> 16) & 1u);
  return (unsigned short)(u >> 16);
}

// packed RNE f32->bf16 pair: low16 = bf16(lo), high16 = bf16(hi)
__device__ __forceinline__ unsigned cvt_pk_bf16(float lo, float hi) {
  unsigned r;
  asm("v_cvt_pk_bf16_f32 %0, %1, %2" : "=v"(r) : "v"(lo), "v"(hi));
  return r;
}

// -------- weight transpose+cvt: W fp32 [512][256] -> WT bf16 [256][512] --------
__global__ __launch_bounds__(256) void kt_transpose(const float* __restrict__ Wg,
                                                    unsigned short* __restrict__ WT) {
  __shared__ unsigned short sm[32][33];
  int tid = threadIdx.x;
  int bk = blockIdx.x >> 3;  // k tile
  int bn = blockIdx.x & 7;   // n tile
  int k0 = bk * 32, n0 = bn * 32;
  int r = tid >> 3, c4 = (tid & 7) * 4;
  const float* src = Wg + (size_t)(k0 + r) * DOUT + n0 + c4;
#pragma unroll
  for (int x = 0; x < 4; ++x) sm[r][c4 + x] = f2bf_rne(src[x]);
  __syncthreads();
  unsigned short* dst = WT + (size_t)(n0 + r) * DIN + k0 + c4;
#pragma unroll
  for (int x = 0; x < 4; ++x) dst[x] = sm[c4 + x][r];
}

// -------- X fp32 [8192][512] -> Xb bf16 (aliases accg workspace; gemm1 reads it,
//          then accg memset happens AFTER gemm1) --------
__global__ __launch_bounds__(256) void kt_cvtx(const float* __restrict__ X,
                                               unsigned short* __restrict__ Xb) {
  int g = blockIdx.x * 256 + threadIdx.x;  // one 8-float group per thread; 2048*256*8 = 8192*512
  const float4* p = (const float4*)(X + (size_t)g * 8);
  float4 a = p[0], b = p[1];
  union { unsigned u[4]; short8 s8; } r;
  r.u[0] = cvt_pk_bf16(a.x, a.y);
  r.u[1] = cvt_pk_bf16(a.z, a.w);
  r.u[2] = cvt_pk_bf16(b.x, b.y);
  r.u[3] = cvt_pk_bf16(b.z, b.w);
  *(short8*)(Xb + (size_t)g * 8) = r.s8;
}

// -- GEMM1 (MFMA, all-bf16 operands): WhT[d][i] = sum_k X[i][k] W[k][d];
//    Wh1/Wh2 row dots via shfl + atomicAdd, PRE-SCALED by log2(e) so the attn
//    kernel can use v_exp_f32 (exp2) directly. 512 blocks = 2/CU. --
__global__ __launch_bounds__(256) void kt_gemm1(const unsigned short* __restrict__ Xb,
                                                const unsigned short* __restrict__ WT,
                                                const float* __restrict__ Ab,
                                                unsigned short* __restrict__ WhT,
                                                float* __restrict__ Wh1,
                                                float* __restrict__ Wh2) {
  int tid = threadIdx.x;
  int w = tid >> 6, lane = tid & 63;
  int col = lane & 15, q = lane >> 4;
  int ib = blockIdx.x & 127;  // i block (64 each); ib and ib+128 land on same XCD -> X L2 reuse
  int db = blockIdx.x >> 7;   // d block (64 each)
  int i0 = ib * 64;
  int drow = db * 64 + w * 16 + col;  // A row (d)
  const unsigned short* abase = WT + (size_t)drow * DIN + q * 8;
  const unsigned short* xbase = Xb + (size_t)(i0 + col) * DIN + q * 8;
  floatx4 acc[4];
#pragma unroll
  for (int t = 0; t < 4; ++t) acc[t] = (floatx4)(0.0f);
  for (int k0 = 0; k0 < DIN; k0 += 32) {
    short8 af = *(const short8*)(abase + k0);
#pragma unroll
    for (int t = 0; t < 4; ++t) {
      short8 bf = *(const short8*)(xbase + (size_t)t * 16 * DIN + k0);
      acc[t] = __builtin_amdgcn_mfma_f32_16x16x32_bf16(af, bf, acc[t], 0, 0, 0);
    }
  }
  // D: col=lane&15 -> i; row=q*4+r -> d  (layout verified in prior session vs anchor)
  int dq = db * 64 + w * 16 + q * 4;
  float a1v[4], a2v[4];
#pragma unroll
  for (int r = 0; r < 4; ++r) {
    a1v[r] = Ab[dq + r] * LOG2E;
    a2v[r] = Ab[DOUT + dq + r] * LOG2E;
  }
#pragma unroll
  for (int t = 0; t < 4; ++t) {
    floatx4 v = acc[t];
    int icol = i0 + t * 16 + col;
#pragma unroll
    for (int r = 0; r < 4; ++r) WhT[(size_t)(dq + r) * NN + icol] = f2bf_rne(v[r]);
    float p1 = v[0] * a1v[0] + v[1] * a1v[1] + v[2] * a1v[2] + v[3] * a1v[3];
    float p2 = v[0] * a2v[0] + v[1] * a2v[1] + v[2] * a2v[2] + v[3] * a2v[3];
    p1 += __shfl_xor(p1, 16);
    p1 += __shfl_xor(p1, 32);
    p2 += __shfl_xor(p2, 16);
    p2 += __shfl_xor(p2, 32);
    if (q == 0) {
      atomicAdd(&Wh1[icol], p1);
      atomicAdd(&Wh2[icol], p2);
    }
  }
}

// ---------------- fused masked-softmax attention (rank-1 scores) ----------------
// Max-free softmax is exact: |score*log2e| <= ~15, exp2 can't overflow; masked w = 0.
// P weights rounded to bf16 (v_cvt_pk_bf16_f32, RNE) for MFMA; denominator sums
// the *rounded* weights. Wh1/Wh2 arrive pre-scaled by log2(e).
__device__ __forceinline__ short8 build_a(int4 pa, int4 pb, float wh1, floatx4 w2a,
                                          floatx4 w2b, float& lsum) {
  int av[8] = {pa.x, pa.y, pa.z, pa.w, pb.x, pb.y, pb.z, pb.w};
  float w2[8] = {w2a[0], w2a[1], w2a[2], w2a[3], w2b[0], w2b[1], w2b[2], w2b[3]};
  float wv[8];
#pragma unroll
  for (int e = 0; e < 8; ++e) {
    float sc = wh1 + w2[e];
    sc = fmaxf(sc, 0.2f * sc);  // LeakyReLU (commutes with the positive log2e scale)
    float ex = __builtin_amdgcn_exp2f(sc);
    wv[e] = (av[e] != 0) ? ex : 0.0f;
  }
  union { unsigned u[4]; short8 s8; } r;
#pragma unroll
  for (int p = 0; p < 4; ++p) {
    unsigned pk = cvt_pk_bf16(wv[2 * p], wv[2 * p + 1]);
    r.u[p] = pk;
    lsum += __uint_as_float(pk << 16) + __uint_as_float(pk & 0xffff0000u);
  }
  return r.s8;
}

// New structure vs prior round: each wave owns 32 DISTINCT rows x all 256 d
// (scores + adj once, no 2x duplicate across d-half waves), double-buffered LDS
// tile -> ONE barrier per 32-j step, NSPLIT=8 (32 steps, strip pinned per XCD).
__global__ __launch_bounds__(256, 2) void kt_attn(const int* __restrict__ adj,
                                                  const unsigned short* __restrict__ WhT,
                                                  const float* __restrict__ Wh1,
                                                  const float* __restrict__ Wh2,
                                                  float* __restrict__ accg,
                                                  float* __restrict__ lg) {
  __shared__ __align__(16) unsigned short tileB[2][DOUT * 32];  // 2 x 16 KB, XOR-swizzled rows
  int tid = threadIdx.x;
  int w = tid >> 6, lane = tid & 63;
  int col = lane & 15, q = lane >> 4;
  int s = blockIdx.x & (NSPLIT - 1);  // strip -> XCD (b%8): WhT strip stays in that L2
  int ib = blockIdx.x >> 3;
  int i0 = ib * 128;
  int jb = s * STRIP;

  int r0 = i0 + w * 32 + col;  // this lane's first score row
  float wh1r0 = Wh1[r0];
  float wh1r1 = Wh1[r0 + 16];

  // staging: thread owns WhT row d = tid; 32-j slices, XOR chunk swizzle
  int fsw = (tid >> 1) & 3;
  const unsigned short* gsrc = WhT + (size_t)tid * NN + jb;
  unsigned short* lrow0 = &tileB[0][tid * 32];

  // reader: row d = T*16 + col, j-chunk q at physical chunk q^fc  (fc == (d>>1)&3)
  int fc = (col >> 1) & 3;
  const unsigned short* bb0 = &tileB[0][col * 32 + ((q ^ fc) * 8)];

  const int* aptr0 = adj + ((size_t)r0 << 13) + jb + q * 8;
  const int* aptr1 = adj + ((size_t)(r0 + 16) << 13) + jb + q * 8;
  const float* wp = Wh2 + jb + q * 8;

  floatx4 acc0[16], acc1[16];
#pragma unroll
  for (int t = 0; t < 16; ++t) {
    acc0[t] = (floatx4)(0.0f);
    acc1[t] = (floatx4)(0.0f);
  }
  float lp0 = 0.f, lp1 = 0.f;

  // prologue prefetch: tile 0 rows + adj + Wh2 for step 0
  short8 st[4];
#pragma unroll
  for (int m = 0; m < 4; ++m) st[m] = *(const short8*)(gsrc + m * 8);
  int4 a0a = *(const int4*)aptr0;
  int4 a0b = *(const int4*)(aptr0 + 4);
  int4 a1a = *(const int4*)aptr1;
  int4 a1b = *(const int4*)(aptr1 + 4);
  floatx4 w2a = *(const floatx4*)wp;
  floatx4 w2b = *(const floatx4*)(wp + 4);

#pragma unroll 1
  for (int k = 0; k < NSTEP; ++k) {
    int bsel = (k & 1) * (DOUT * 32);  // buffer offset in shorts (no dynamic array idx)
    unsigned short* lw = lrow0 + bsel;
#pragma unroll
    for (int m = 0; m < 4; ++m) *(short8*)(lw + ((m ^ fsw) * 8)) = st[m];
    __syncthreads();  // single barrier per step: dbuf makes write(k+1) vs read(k) safe
    if (k + 1 < NSTEP) {
      const unsigned short* gs = gsrc + (size_t)(k + 1) * 32;
#pragma unroll
      for (int m = 0; m < 4; ++m) st[m] = *(const short8*)(gs + m * 8);
    }
    short8 af0 = build_a(a0a, a0b, wh1r0, w2a, w2b, lp0);
    short8 af1 = build_a(a1a, a1b, wh1r1, w2a, w2b, lp1);
    if (k + 1 < NSTEP) {  // prefetch next adj + Wh2 under the MFMA phase
      int jn = (k + 1) * 32;
      a0a = *(const int4*)(aptr0 + jn);
      a0b = *(const int4*)(aptr0 + jn + 4);
      a1a = *(const int4*)(aptr1 + jn);
      a1b = *(const int4*)(aptr1 + jn + 4);
      w2a = *(const floatx4*)(wp + jn);
      w2b = *(const floatx4*)(wp + jn + 4);
    }
    const unsigned short* br = bb0 + bsel;
#pragma unroll
    for (int h = 0; h < 4; ++h) {  // batches of 4 to bound bf liveness
      short8 bf[4];
#pragma unroll
      for (int t = 0; t < 4; ++t) bf[t] = *(const short8*)(br + (h * 4 + t) * 512);
#pragma unroll
      for (int t = 0; t < 4; ++t) {
        acc0[h * 4 + t] =
            __builtin_amdgcn_mfma_f32_16x16x32_bf16(af0, bf[t], acc0[h * 4 + t], 0, 0, 0);
        acc1[h * 4 + t] =
            __builtin_amdgcn_mfma_f32_16x16x32_bf16(af1, bf[t], acc1[h * 4 + t], 0, 0, 0);
      }
    }
  }

  // l reduction across q groups; rows are unique per wave now -> every wave adds
  lp0 += __shfl_xor(lp0, 16);
  lp0 += __shfl_xor(lp0, 32);
  lp1 += __shfl_xor(lp1, 16);
  lp1 += __shfl_xor(lp1, 32);
  if (lane < 16) {
    atomicAdd(&lg[i0 + w * 32 + lane], lp0);
    atomicAdd(&lg[i0 + w * 32 + 16 + lane], lp1);
  }
  // fp32 partial merge via coalesced atomics (8 strips per address)
#pragma unroll
  for (int T = 0; T < 16; ++T) {
    floatx4 v0 = acc0[T];
    floatx4 v1 = acc1[T];
    int dcol = T * 16 + col;
    int irow0 = i0 + w * 32 + q * 4;
#pragma unroll
    for (int r = 0; r < 4; ++r) atomicAdd(&accg[(size_t)(irow0 + r) * DOUT + dcol], v0[r]);
#pragma unroll
    for (int r = 0; r < 4; ++r)
      atomicAdd(&accg[(size_t)(irow0 + 16 + r) * DOUT + dcol], v1[r]);
  }
}

// ---------------- normalize + ELU -> fp32 out (float4-vectorized) ----------------
__global__ __launch_bounds__(256) void kt_merge(const float* __restrict__ accg,
                                                const float* __restrict__ lg,
                                                float* __restrict__ out) {
  int g = blockIdx.x * 256 + threadIdx.x;  // one 4-float group; 2048*256*4 = 8192*256
  int i = g >> 6;
  float inv = 1.0f / lg[i];
  float4 v = *(const float4*)(accg + (size_t)g * 4);
  float o[4] = {v.x * inv, v.y * inv, v.z * inv, v.w * inv};
#pragma unroll
  for (int r = 0; r < 4; ++r) o[r] = o[r] > 0.f ? o[r] : (__expf(o[r]) - 1.f);
  *(float4*)(out + (size_t)g * 4) = make_float4(o[0], o[1], o[2], o[3]);
}

extern "C" void kernel_launch(void* const* d_in, const int* in_sizes, int n_in,
                              void* d_out, int out_size, void* d_ws, size_t ws_size,
                              hipStream_t stream) {
  const float* X = (const float*)d_in[0];   // input fp32 [8192][512]
  const int* adj = (const int*)d_in[1];     // int32 [8192][8192]
  const float* Wg = (const float*)d_in[2];  // weight fp32 [512][256]
  const float* Ab = (const float*)d_in[3];  // a fp32 [512]
  float* out = (float*)d_out;               // fp32 [8192][256]

  // workspace: accg | lg | Wh1 | Wh2 | WT | WhT  (~12.4 MB, unchanged footprint).
  // Xb (bf16 X, 8 MB) EXACTLY aliases accg: cvtx->gemm1 read it, then the accg
  // memset (moved to after gemm1) reclaims the region for the attn atomics.
  char* ws = (char*)d_ws;
  float* accg = (float*)ws;                       // 8 MB
  unsigned short* Xb = (unsigned short*)ws;       // alias of accg (8192*512*2 = 8 MB)
  size_t off = (size_t)NN * DOUT * 4;
  float* lg = (float*)(ws + off);
  off += (size_t)NN * 4;
  float* Wh1 = (float*)(ws + off);
  off += (size_t)NN * 4;
  float* Wh2 = (float*)(ws + off);
  off += (size_t)NN * 4;
  unsigned short* WT = (unsigned short*)(ws + off);
  off += (size_t)DOUT * DIN * 2;  // 256 KB
  unsigned short* WhT = (unsigned short*)(ws + off);
  off += (size_t)DOUT * NN * 2;  // 4 MB

  hipMemsetAsync(Wh1, 0, (size_t)NN * 8, stream);  // Wh1+Wh2 (contiguous) for gemm1 atomics
  kt_cvtx<<<2048, 256, 0, stream>>>(X, Xb);
  kt_transpose<<<128, 256, 0, stream>>>(Wg, WT);
  kt_gemm1<<<512, 256, 0, stream>>>(Xb, WT, Ab, WhT, Wh1, Wh2);
  hipMemsetAsync(ws, 0, (size_t)NN * DOUT * 4 + (size_t)NN * 4, stream);  // accg+lg
  kt_attn<<<(NN / 128) * NSPLIT, 256, 0, stream>>>(adj, WhT, Wh1, Wh2, accg, lg);
  kt_merge<<<2048, 256, 0, stream>>>(accg, lg, out);
}